// Round 5
// baseline (113.769 us; speedup 1.0000x reference)
//
#include <hip/hip_runtime.h>
#include <hip/hip_bf16.h>

#define K_DIM 16384
#define M_DIM 512
#define N_DIM 2560
#define BN 64
#define BK 64
#define KSPLIT 8
#define KCH (K_DIM / KSPLIT)   // 2048
#define NK (KCH / BK)          // 32

typedef float f32x4 __attribute__((ext_vector_type(4)));
typedef __bf16 bf16x8 __attribute__((ext_vector_type(8)));

__device__ __forceinline__ unsigned short f2bf(float f){
  union { float f; unsigned u; } v; v.f = f;
  unsigned r = v.u + 0x7FFFu + ((v.u >> 16) & 1u);
  return (unsigned short)(r >> 16);
}
__device__ __forceinline__ unsigned bfpack2(float lo, float hi){
  return (unsigned)f2bf(lo) | ((unsigned)f2bf(hi) << 16);
}

// K1: w_mean[c] = mean_f conv1_w[f][c]; b_mean = mean(conv1_b)
__global__ __launch_bounds__(256)
void prep_kernel(const float* __restrict__ conv1_w, const float* __restrict__ conv1_b,
                 float* __restrict__ w_mean, float* __restrict__ b_mean)
{
  int c = blockIdx.x * 256 + threadIdx.x;
  if (c < K_DIM){
    float s = 0.f;
    #pragma unroll
    for (int f = 0; f < 10; ++f) s += conv1_w[f * K_DIM + c];
    w_mean[c] = s * 0.1f;
  }
  if (blockIdx.x == 0 && threadIdx.x == 0){
    float s = 0.f;
    #pragma unroll
    for (int f = 0; f < 10; ++f) s += conv1_b[f];
    *b_mean = s * 0.1f;
  }
}

// K2: pooled[row] = x[row,:].w_mean + b_mean  AND  xbf[row,:] = bf16(x[row,:])
__global__ __launch_bounds__(256)
void pooled_kernel(const float* __restrict__ X, const float* __restrict__ w_mean,
                   const float* __restrict__ b_mean, float* __restrict__ pooled,
                   unsigned short* __restrict__ xbf)
{
  const int row = blockIdx.x;
  const int tid = threadIdx.x;
  const float* xr = X + (size_t)row * K_DIM;
  unsigned short* xb = xbf + (size_t)row * K_DIM;
  float s = 0.f;
  #pragma unroll 2
  for (int i = 0; i < 8; ++i){
    int idx = (tid + 256 * i) * 8;
    float4 a0 = *(const float4*)(xr + idx);
    float4 a1 = *(const float4*)(xr + idx + 4);
    float4 w0 = *(const float4*)(w_mean + idx);
    float4 w1 = *(const float4*)(w_mean + idx + 4);
    s += a0.x*w0.x + a0.y*w0.y + a0.z*w0.z + a0.w*w0.w
       + a1.x*w1.x + a1.y*w1.y + a1.z*w1.z + a1.w*w1.w;
    uint4 p;
    p.x = bfpack2(a0.x, a0.y); p.y = bfpack2(a0.z, a0.w);
    p.z = bfpack2(a1.x, a1.y); p.w = bfpack2(a1.z, a1.w);
    *(uint4*)(xb + idx) = p;
  }
  #pragma unroll
  for (int off = 32; off; off >>= 1) s += __shfl_down(s, off);
  __shared__ float red[4];
  if ((tid & 63) == 0) red[tid >> 6] = s;
  __syncthreads();
  if (tid == 0) pooled[row] = red[0] + red[1] + red[2] + red[3] + *b_mean;
}

// K3: gates
__global__ __launch_bounds__(512)
void gates_kernel(const float* __restrict__ pooled, const float* __restrict__ fw,
                  const float* __restrict__ fb, const float* __restrict__ aw,
                  float* __restrict__ gates)
{
  __shared__ float ps[512];
  int tid = threadIdx.x;
  ps[tid] = pooled[tid];
  __syncthreads();
  int b = tid >> 5, s = tid & 31;
  float z = fb[s];
  #pragma unroll
  for (int t = 0; t < 32; ++t) z += ps[b * 32 + t] * fw[s * 32 + t];
  float mx = z;
  #pragma unroll
  for (int off = 16; off; off >>= 1) mx = fmaxf(mx, __shfl_xor(mx, off));
  float e = expf(z - mx);
  float sum = e;
  #pragma unroll
  for (int off = 16; off; off >>= 1) sum += __shfl_xor(sum, off);
  float sm = e / sum;
  float relu = z > 0.f ? z : 0.f;
  float sig = 1.f / (1.f + expf(-z));
  gates[tid] = aw[0] * relu + aw[1] * sig + aw[2] * sm;
}

// K4: BM=512 (full M, W read exactly ONCE), BN=64, BK=64, 8 waves = 8 m-waves.
// Grid 40*8 flat; kz = id&7 pins K-slice to one XCD (X bf16 k-slice 2MB L2-resident).
// A staged by global_load_lds dwordx4, LDS linear dest + pre-swizzled global source.
// B (fp32) reg-staged with fp32->bf16 cvt; next-tile B loads issued under compute.
// mode 0: raw partial per kz; mode 2: atomicAdd into outp.
__global__ __launch_bounds__(512, 4)
void gemm_kernel(const unsigned short* __restrict__ Abf, const float* __restrict__ W,
                 float* __restrict__ outp, int mode)
{
  __shared__ __align__(16) char smem[73728];   // A [512][64]bf16 swz = 64KB; B 8KB
  const int tid  = threadIdx.x;
  const int lane = tid & 63;
  const int wv   = tid >> 6;
  const int wm   = wv * 64;          // 8 m-waves, wave tile 64m x 64n

  const int id = blockIdx.x;
  const int kz = id & 7;
  const int n0 = (id >> 3) * BN;
  const int kbase = kz * KCH;

  f32x4 acc[4][4] = {};

  // A staging: per thread 8 gll issues; LDS linear chunk u = j*512 + tid
  //   row = u>>3 = j*64 + wv*8 + (lane>>3); c8 = lane&7.
  //   LDS[row][c8] must hold A[row][c8 ^ (row&7)]; row&7 == lane>>3.
  const int arow0 = wv * 8 + (lane >> 3);
  const int ac8   = (lane & 7) ^ (lane >> 3);
  const unsigned short* asrc = Abf + (size_t)arow0 * K_DIM + ac8 * 8;

  // B staging: thread -> row = tid>>3 (0..63), chunk c8 = tid&7
  const int brow = tid >> 3;
  const int bc8  = tid & 7;
  const float* bsrc = W + (size_t)(n0 + brow) * K_DIM + bc8 * 8;
  char* bdst = smem + 65536 + brow * 128 + ((bc8 * 16) ^ ((brow & 7) << 4));

  // prologue: B regs for kt=0
  float4 rb0 = *(const float4*)(bsrc + kbase);
  float4 rb1 = *(const float4*)(bsrc + kbase + 4);

  for (int kt = 0; kt < NK; ++kt){
    const int k0 = kbase + kt * BK;
    // issue A global->LDS (8 x 1KB per wave), linear dest, pre-swizzled src
    #pragma unroll
    for (int j = 0; j < 8; ++j){
      __builtin_amdgcn_global_load_lds(
        (const __attribute__((address_space(1))) void*)(asrc + (size_t)j * 64 * K_DIM + k0),
        (__attribute__((address_space(3))) void*)(smem + (j * 512 + wv * 64) * 16),
        16, 0, 0);
    }
    // write B tile from regs (loaded previous iter), swizzled
    uint4 ub;
    ub.x = bfpack2(rb0.x, rb0.y); ub.y = bfpack2(rb0.z, rb0.w);
    ub.z = bfpack2(rb1.x, rb1.y); ub.w = bfpack2(rb1.z, rb1.w);
    *(uint4*)bdst = ub;
    __syncthreads();                       // drains vmcnt+lgkm: A & B tile ready
    if (kt + 1 < NK){                      // prefetch next B under compute
      rb0 = *(const float4*)(bsrc + k0 + BK);
      rb1 = *(const float4*)(bsrc + k0 + BK + 4);
    }
    #pragma unroll
    for (int kk = 0; kk < 2; ++kk){
      bf16x8 af[4], bfv[4];
      const int kbyte = kk * 64 + (lane >> 4) * 16;
      #pragma unroll
      for (int i = 0; i < 4; ++i){
        int row = wm + i * 16 + (lane & 15);
        af[i] = *(const bf16x8*)(smem + row * 128 + (kbyte ^ ((row & 7) << 4)));
        int rowb = i * 16 + (lane & 15);
        bfv[i] = *(const bf16x8*)(smem + 65536 + rowb * 128 + (kbyte ^ ((rowb & 7) << 4)));
      }
      #pragma unroll
      for (int i = 0; i < 4; ++i)
        #pragma unroll
        for (int j = 0; j < 4; ++j)
          acc[i][j] = __builtin_amdgcn_mfma_f32_16x16x32_bf16(af[i], bfv[j], acc[i][j], 0, 0, 0);
    }
    __syncthreads();
  }

  if (mode == 0){
    float* P = outp + (size_t)kz * M_DIM * N_DIM;
    #pragma unroll
    for (int i = 0; i < 4; ++i){
      int rbase = wm + i * 16 + (lane >> 4) * 4;
      #pragma unroll
      for (int j = 0; j < 4; ++j){
        int col = n0 + j * 16 + (lane & 15);
        #pragma unroll
        for (int r2 = 0; r2 < 4; ++r2)
          P[(size_t)(rbase + r2) * N_DIM + col] = acc[i][j][r2];
      }
    }
  } else {
    #pragma unroll
    for (int i = 0; i < 4; ++i){
      int rbase = wm + i * 16 + (lane >> 4) * 4;
      #pragma unroll
      for (int j = 0; j < 4; ++j){
        int col = n0 + j * 16 + (lane & 15);
        #pragma unroll
        for (int r2 = 0; r2 < 4; ++r2)
          atomicAdd(&outp[(size_t)(rbase + r2) * N_DIM + col], acc[i][j][r2]);
      }
    }
  }
}

// K5a: out[m,n] = gates[m] * (sum_z partial[z,m,n] + bias[n])
__global__ __launch_bounds__(256)
void reduce_kernel(const float* __restrict__ part, const float* __restrict__ gates,
                   const float* __restrict__ bias, float* __restrict__ out, int ksplit)
{
  int i4 = blockIdx.x * 256 + threadIdx.x;
  if (i4 >= M_DIM * N_DIM / 4) return;
  size_t off = (size_t)i4 * 4;
  int m = (int)(off / N_DIM);
  int n = (int)(off % N_DIM);
  float sx = 0.f, sy = 0.f, sz = 0.f, sw = 0.f;
  for (int z = 0; z < ksplit; ++z){
    float4 p = *(const float4*)(part + (size_t)z * M_DIM * N_DIM + off);
    sx += p.x; sy += p.y; sz += p.z; sw += p.w;
  }
  float4 bv = *(const float4*)(bias + n);
  float g = gates[m];
  float4 o;
  o.x = g * (sx + bv.x); o.y = g * (sy + bv.y);
  o.z = g * (sz + bv.z); o.w = g * (sw + bv.w);
  *(float4*)(out + off) = o;
}

// K5b: finalize after atomic accumulation
__global__ __launch_bounds__(256)
void finalize_kernel(float* __restrict__ out, const float* __restrict__ gates,
                     const float* __restrict__ bias)
{
  int i4 = blockIdx.x * 256 + threadIdx.x;
  if (i4 >= M_DIM * N_DIM / 4) return;
  size_t off = (size_t)i4 * 4;
  int m = (int)(off / N_DIM);
  int n = (int)(off % N_DIM);
  float4 o = *(const float4*)(out + off);
  float4 bv = *(const float4*)(bias + n);
  float g = gates[m];
  o.x = g * (o.x + bv.x); o.y = g * (o.y + bv.y);
  o.z = g * (o.z + bv.z); o.w = g * (o.w + bv.w);
  *(float4*)(out + off) = o;
}

extern "C" void kernel_launch(void* const* d_in, const int* in_sizes, int n_in,
                              void* d_out, int out_size, void* d_ws, size_t ws_size,
                              hipStream_t stream)
{
  const float* input   = (const float*)d_in[0];
  const float* aw      = (const float*)d_in[2];
  const float* conv1_w = (const float*)d_in[3];
  const float* conv1_b = (const float*)d_in[4];
  const float* G3_w    = (const float*)d_in[5];
  const float* G3_b    = (const float*)d_in[6];
  const float* ffnn1_w = (const float*)d_in[7];
  const float* ffnn1_b = (const float*)d_in[8];
  float* out = (float*)d_out;

  float* wsf    = (float*)d_ws;
  float* w_mean = wsf;               // 16384 f
  float* pooled = wsf + 16384;       // 512 f
  float* gates  = wsf + 16896;       // 512 f
  float* b_mean = wsf + 17408;       // 64 f pad
  unsigned short* xbf = (unsigned short*)(wsf + 17472);        // 512*16384 bf16 = 16MB
  float* partial = wsf + 17472 + (size_t)M_DIM * K_DIM / 2;    // 8 * 512*2560 f

  const size_t need_det = ((size_t)17472 + (size_t)M_DIM * K_DIM / 2
                           + (size_t)KSPLIT * M_DIM * N_DIM) * 4;   // ~58.8MB

  prep_kernel<<<64, 256, 0, stream>>>(conv1_w, conv1_b, w_mean, b_mean);
  pooled_kernel<<<512, 256, 0, stream>>>(input, w_mean, b_mean, pooled, xbf);
  gates_kernel<<<1, 512, 0, stream>>>(pooled, ffnn1_w, ffnn1_b, aw, gates);

  const int n4 = M_DIM * N_DIM / 4;
  const int grid = (N_DIM / BN) * KSPLIT;   // 40*8 = 320
  if (ws_size >= need_det){
    gemm_kernel<<<grid, 512, 0, stream>>>(xbf, G3_w, partial, 0);
    reduce_kernel<<<(n4 + 255) / 256, 256, 0, stream>>>(partial, gates, G3_b, out, KSPLIT);
  } else {
    hipMemsetAsync(d_out, 0, (size_t)out_size * sizeof(float), stream);
    gemm_kernel<<<grid, 512, 0, stream>>>(xbf, G3_w, out, 2);
    finalize_kernel<<<(n4 + 255) / 256, 256, 0, stream>>>(out, gates, G3_b);
  }
}

// Round 6
// 111.243 us; speedup vs baseline: 1.0227x; 1.0227x over previous
//
#include <hip/hip_runtime.h>
#include <hip/hip_bf16.h>

#define K_DIM 16384
#define M_DIM 512
#define N_DIM 2560
#define BM 512
#define BN 128
#define BK 64
#define KSPLIT 8
#define KCH (K_DIM / KSPLIT)   // 2048
#define NK (KCH / BK)          // 32

typedef float f32x4 __attribute__((ext_vector_type(4)));
typedef __bf16 bf16x8 __attribute__((ext_vector_type(8)));

__device__ __forceinline__ unsigned short f2bf(float f){
  union { float f; unsigned u; } v; v.f = f;
  unsigned r = v.u + 0x7FFFu + ((v.u >> 16) & 1u);
  return (unsigned short)(r >> 16);
}
__device__ __forceinline__ unsigned bfpack2(float lo, float hi){
  return (unsigned)f2bf(lo) | ((unsigned)f2bf(hi) << 16);
}

// K1: w_mean[c] = mean_f conv1_w[f][c]; b_mean = mean(conv1_b)
__global__ __launch_bounds__(256)
void prep_kernel(const float* __restrict__ conv1_w, const float* __restrict__ conv1_b,
                 float* __restrict__ w_mean, float* __restrict__ b_mean)
{
  int c = blockIdx.x * 256 + threadIdx.x;
  if (c < K_DIM){
    float s = 0.f;
    #pragma unroll
    for (int f = 0; f < 10; ++f) s += conv1_w[f * K_DIM + c];
    w_mean[c] = s * 0.1f;
  }
  if (blockIdx.x == 0 && threadIdx.x == 0){
    float s = 0.f;
    #pragma unroll
    for (int f = 0; f < 10; ++f) s += conv1_b[f];
    *b_mean = s * 0.1f;
  }
}

// K2: pooled[row] = x[row,:].w_mean + b_mean  AND  xbf[row,:] = bf16(x[row,:])
__global__ __launch_bounds__(256)
void pooled_kernel(const float* __restrict__ X, const float* __restrict__ w_mean,
                   const float* __restrict__ b_mean, float* __restrict__ pooled,
                   unsigned short* __restrict__ xbf)
{
  const int row = blockIdx.x;
  const int tid = threadIdx.x;
  const float* xr = X + (size_t)row * K_DIM;
  unsigned short* xb = xbf + (size_t)row * K_DIM;
  float s = 0.f;
  #pragma unroll 2
  for (int i = 0; i < 8; ++i){
    int idx = (tid + 256 * i) * 8;
    float4 a0 = *(const float4*)(xr + idx);
    float4 a1 = *(const float4*)(xr + idx + 4);
    float4 w0 = *(const float4*)(w_mean + idx);
    float4 w1 = *(const float4*)(w_mean + idx + 4);
    s += a0.x*w0.x + a0.y*w0.y + a0.z*w0.z + a0.w*w0.w
       + a1.x*w1.x + a1.y*w1.y + a1.z*w1.z + a1.w*w1.w;
    uint4 p;
    p.x = bfpack2(a0.x, a0.y); p.y = bfpack2(a0.z, a0.w);
    p.z = bfpack2(a1.x, a1.y); p.w = bfpack2(a1.z, a1.w);
    *(uint4*)(xb + idx) = p;
  }
  #pragma unroll
  for (int off = 32; off; off >>= 1) s += __shfl_down(s, off);
  __shared__ float red[4];
  if ((tid & 63) == 0) red[tid >> 6] = s;
  __syncthreads();
  if (tid == 0) pooled[row] = red[0] + red[1] + red[2] + red[3] + *b_mean;
}

// K3: gates
__global__ __launch_bounds__(512)
void gates_kernel(const float* __restrict__ pooled, const float* __restrict__ fw,
                  const float* __restrict__ fb, const float* __restrict__ aw,
                  float* __restrict__ gates)
{
  __shared__ float ps[512];
  int tid = threadIdx.x;
  ps[tid] = pooled[tid];
  __syncthreads();
  int b = tid >> 5, s = tid & 31;
  float z = fb[s];
  #pragma unroll
  for (int t = 0; t < 32; ++t) z += ps[b * 32 + t] * fw[s * 32 + t];
  float mx = z;
  #pragma unroll
  for (int off = 16; off; off >>= 1) mx = fmaxf(mx, __shfl_xor(mx, off));
  float e = expf(z - mx);
  float sum = e;
  #pragma unroll
  for (int off = 16; off; off >>= 1) sum += __shfl_xor(sum, off);
  float sm = e / sum;
  float relu = z > 0.f ? z : 0.f;
  float sig = 1.f / (1.f + expf(-z));
  gates[tid] = aw[0] * relu + aw[1] * sig + aw[2] * sm;
}

// K4: BM=512 (full M, W read ONCE), BN=128, BK=64. 8 waves, wave tile 128x64
// (acc 8x4 -> 43.7 FLOP per LDS byte). Grid 160 flat, kz=id&7 XCD-pinned.
// A: global_load_lds dwordx4, DOUBLE-buffered (stage kt+1 issued before compute kt,
//    L2 latency hidden under MFMA). Linear LDS dest + pre-swizzled global src.
// B: fp32 reg-prefetch 2 steps deep, cvt->bf16, single LDS buffer republished/step.
// mode 0: raw partial per kz; mode 2: atomicAdd into outp.
__global__ __launch_bounds__(512, 2)
void gemm_kernel(const unsigned short* __restrict__ Abf, const float* __restrict__ W,
                 float* __restrict__ outp, int mode)
{
  __shared__ __align__(16) char smem[147456];  // A dbuf 2x64KB + B 16KB
  char* bufA0 = smem;
  char* bufA1 = smem + 65536;
  char* bufB  = smem + 131072;

  const int tid  = threadIdx.x;
  const int lane = tid & 63;
  const int wv   = tid >> 6;
  const int wm   = (wv >> 1) * 128;     // 4 m-groups of 128
  const int wn   = (wv & 1) * 64;       // 2 n-groups of 64

  const int id = blockIdx.x;
  const int kz = id & 7;
  const int n0 = (id >> 3) * BN;
  const int kbase = kz * KCH;

  f32x4 acc[8][4] = {};

  // A staging: per thread 8 gll of 16B. Linear LDS chunk u = j*512 + wv*64 + lane
  //   -> row = j*64 + wv*8 + (lane>>3), c8 = lane&7. LDS[row][c8] must hold
  //   A[row][c8 ^ (row&7)]; row&7 == lane>>3 (j*64, wv*8 are multiples of 8).
  const int arow0 = wv * 8 + (lane >> 3);
  const int ac8   = (lane & 7) ^ (lane >> 3);
  const unsigned short* asrc = Abf + (size_t)arow0 * K_DIM + ac8 * 8;
  const int adst_off = (wv * 64 + lane) * 16;

  // B staging: thread -> row = tid>>2 (0..127), kc = (tid&3)*16 fp32 elems
  const int brow = tid >> 2;
  const int bkc  = (tid & 3) * 16;
  const float* bsrc = W + (size_t)(n0 + brow) * K_DIM + kbase + bkc;
  char* bdst0 = bufB + brow * 128 + (((bkc * 2)     ) ^ ((brow & 7) << 4));
  char* bdst1 = bufB + brow * 128 + (((bkc * 2) + 16) ^ ((brow & 7) << 4));

  auto stageA = [&](char* dst, int k0){
    #pragma unroll
    for (int j = 0; j < 8; ++j){
      __builtin_amdgcn_global_load_lds(
        (const __attribute__((address_space(1))) void*)(asrc + (size_t)j * 64 * K_DIM + k0),
        (__attribute__((address_space(3))) void*)(dst + j * 8192 + adst_off),
        16, 0, 0);
    }
  };
  auto loadB = [&](int kt, float4* r){
    const float* p = bsrc + kt * BK;
    r[0] = *(const float4*)p;        r[1] = *(const float4*)(p + 4);
    r[2] = *(const float4*)(p + 8);  r[3] = *(const float4*)(p + 12);
  };
  auto writeB = [&](const float4* r){
    uint4 u0, u1;
    u0.x = bfpack2(r[0].x, r[0].y); u0.y = bfpack2(r[0].z, r[0].w);
    u0.z = bfpack2(r[1].x, r[1].y); u0.w = bfpack2(r[1].z, r[1].w);
    u1.x = bfpack2(r[2].x, r[2].y); u1.y = bfpack2(r[2].z, r[2].w);
    u1.z = bfpack2(r[3].x, r[3].y); u1.w = bfpack2(r[3].z, r[3].w);
    *(uint4*)bdst0 = u0;
    *(uint4*)bdst1 = u1;
  };

  // prologue: A(0) staging in flight; B(0) written; rbC = B(1)
  stageA(bufA0, kbase);
  float4 rt[4];  loadB(0, rt);
  writeB(rt);
  float4 rbC[4]; loadB(1, rbC);
  __syncthreads();   // publish B(0), drain A(0) gll

  for (int kt = 0; kt < NK; ++kt){
    char* cur = (kt & 1) ? bufA1 : bufA0;
    char* nxt = (kt & 1) ? bufA0 : bufA1;
    if (kt + 1 < NK) stageA(nxt, kbase + (kt + 1) * BK);   // hidden under compute
    float4 rbN[4];
    if (kt + 2 < NK) loadB(kt + 2, rbN);                   // 2-deep B prefetch

    #pragma unroll
    for (int kk = 0; kk < 2; ++kk){
      bf16x8 af[8], bfv[4];
      const int kbyte = kk * 64 + (lane >> 4) * 16;
      #pragma unroll
      for (int i = 0; i < 8; ++i){
        int row = wm + i * 16 + (lane & 15);
        af[i] = *(const bf16x8*)(cur + row * 128 + (kbyte ^ ((row & 7) << 4)));
      }
      #pragma unroll
      for (int j = 0; j < 4; ++j){
        int row = wn + j * 16 + (lane & 15);
        bfv[j] = *(const bf16x8*)(bufB + row * 128 + (kbyte ^ ((row & 7) << 4)));
      }
      #pragma unroll
      for (int i = 0; i < 8; ++i)
        #pragma unroll
        for (int j = 0; j < 4; ++j)
          acc[i][j] = __builtin_amdgcn_mfma_f32_16x16x32_bf16(af[i], bfv[j], acc[i][j], 0, 0, 0);
    }
    __syncthreads();             // all waves done reading bufB(kt) / bufA[cur]
    if (kt + 1 < NK){
      writeB(rbC);               // B(kt+1) -> LDS
      #pragma unroll
      for (int q = 0; q < 4; ++q) rbC[q] = rbN[q];
      __syncthreads();           // publish B(kt+1); A(kt+1) gll already drained
    }
  }

  if (mode == 0){
    float* P = outp + (size_t)kz * M_DIM * N_DIM;
    #pragma unroll
    for (int i = 0; i < 8; ++i){
      int rbase = wm + i * 16 + (lane >> 4) * 4;
      #pragma unroll
      for (int j = 0; j < 4; ++j){
        int col = n0 + wn + j * 16 + (lane & 15);
        #pragma unroll
        for (int r2 = 0; r2 < 4; ++r2)
          P[(size_t)(rbase + r2) * N_DIM + col] = acc[i][j][r2];
      }
    }
  } else {
    #pragma unroll
    for (int i = 0; i < 8; ++i){
      int rbase = wm + i * 16 + (lane >> 4) * 4;
      #pragma unroll
      for (int j = 0; j < 4; ++j){
        int col = n0 + wn + j * 16 + (lane & 15);
        #pragma unroll
        for (int r2 = 0; r2 < 4; ++r2)
          atomicAdd(&outp[(size_t)(rbase + r2) * N_DIM + col], acc[i][j][r2]);
      }
    }
  }
}

// K5a: out[m,n] = gates[m] * (sum_z partial[z,m,n] + bias[n])
__global__ __launch_bounds__(256)
void reduce_kernel(const float* __restrict__ part, const float* __restrict__ gates,
                   const float* __restrict__ bias, float* __restrict__ out, int ksplit)
{
  int i4 = blockIdx.x * 256 + threadIdx.x;
  if (i4 >= M_DIM * N_DIM / 4) return;
  size_t off = (size_t)i4 * 4;
  int m = (int)(off / N_DIM);
  int n = (int)(off % N_DIM);
  float sx = 0.f, sy = 0.f, sz = 0.f, sw = 0.f;
  for (int z = 0; z < ksplit; ++z){
    float4 p = *(const float4*)(part + (size_t)z * M_DIM * N_DIM + off);
    sx += p.x; sy += p.y; sz += p.z; sw += p.w;
  }
  float4 bv = *(const float4*)(bias + n);
  float g = gates[m];
  float4 o;
  o.x = g * (sx + bv.x); o.y = g * (sy + bv.y);
  o.z = g * (sz + bv.z); o.w = g * (sw + bv.w);
  *(float4*)(out + off) = o;
}

// K5b: finalize after atomic accumulation
__global__ __launch_bounds__(256)
void finalize_kernel(float* __restrict__ out, const float* __restrict__ gates,
                     const float* __restrict__ bias)
{
  int i4 = blockIdx.x * 256 + threadIdx.x;
  if (i4 >= M_DIM * N_DIM / 4) return;
  size_t off = (size_t)i4 * 4;
  int m = (int)(off / N_DIM);
  int n = (int)(off % N_DIM);
  float4 o = *(const float4*)(out + off);
  float4 bv = *(const float4*)(bias + n);
  float g = gates[m];
  o.x = g * (o.x + bv.x); o.y = g * (o.y + bv.y);
  o.z = g * (o.z + bv.z); o.w = g * (o.w + bv.w);
  *(float4*)(out + off) = o;
}

extern "C" void kernel_launch(void* const* d_in, const int* in_sizes, int n_in,
                              void* d_out, int out_size, void* d_ws, size_t ws_size,
                              hipStream_t stream)
{
  const float* input   = (const float*)d_in[0];
  const float* aw      = (const float*)d_in[2];
  const float* conv1_w = (const float*)d_in[3];
  const float* conv1_b = (const float*)d_in[4];
  const float* G3_w    = (const float*)d_in[5];
  const float* G3_b    = (const float*)d_in[6];
  const float* ffnn1_w = (const float*)d_in[7];
  const float* ffnn1_b = (const float*)d_in[8];
  float* out = (float*)d_out;

  float* wsf    = (float*)d_ws;
  float* w_mean = wsf;               // 16384 f
  float* pooled = wsf + 16384;       // 512 f
  float* gates  = wsf + 16896;       // 512 f
  float* b_mean = wsf + 17408;       // 64 f pad
  unsigned short* xbf = (unsigned short*)(wsf + 17472);        // 512*16384 bf16 = 16MB
  float* partial = wsf + 17472 + (size_t)M_DIM * K_DIM / 2;    // 8 * 512*2560 f

  const size_t need_det = ((size_t)17472 + (size_t)M_DIM * K_DIM / 2
                           + (size_t)KSPLIT * M_DIM * N_DIM) * 4;   // ~58.8MB

  prep_kernel<<<64, 256, 0, stream>>>(conv1_w, conv1_b, w_mean, b_mean);
  pooled_kernel<<<512, 256, 0, stream>>>(input, w_mean, b_mean, pooled, xbf);
  gates_kernel<<<1, 512, 0, stream>>>(pooled, ffnn1_w, ffnn1_b, aw, gates);

  const int n4 = M_DIM * N_DIM / 4;
  const int grid = (N_DIM / BN) * KSPLIT;   // 20*8 = 160
  if (ws_size >= need_det){
    gemm_kernel<<<grid, 512, 0, stream>>>(xbf, G3_w, partial, 0);
    reduce_kernel<<<(n4 + 255) / 256, 256, 0, stream>>>(partial, gates, G3_b, out, KSPLIT);
  } else {
    hipMemsetAsync(d_out, 0, (size_t)out_size * sizeof(float), stream);
    gemm_kernel<<<grid, 512, 0, stream>>>(xbf, G3_w, out, 2);
    finalize_kernel<<<(n4 + 255) / 256, 256, 0, stream>>>(out, gates, G3_b);
  }
}